// Round 1
// baseline (353.272 us; speedup 1.0000x reference)
//
#include <hip/hip_runtime.h>
#include <hip/hip_bf16.h>
#include <cstdint>
#include <cstddef>

// YatAttention on MI355X (gfx950).
// B=2, L=2048, E=768, H=12, D=64. GEMMs in bf16 MFMA 16x16x32 (fp32 accum).
// R5: k_attn de-staged. K/VT per head is 256KB (L2-resident, shared by 64
// blocks) -> MFMA fragments read DIRECTLY from global (m169 precedent: don't
// LDS-stage cache-fit data). No K/V LDS, no double-buffer, no __syncthreads
// at all -> LDS 41984->9216B, occupancy-driven latency hiding. XCD swizzle
// keeps each XCD's L2 working set at 3 bh (1.5MB). Mask pre-folded to a
// float bias (k_sq) to drop per-score cmp+cndmask.

typedef __bf16 bf16_t;
typedef __bf16 bf16x8 __attribute__((ext_vector_type(8)));
typedef __bf16 bf16x4 __attribute__((ext_vector_type(4)));
typedef float floatx4 __attribute__((ext_vector_type(4)));

#define DEVI static __device__ __forceinline__

#define Bc 2
#define Lc 2048
#define Ec 768
#define Hc 12
#define Dc 64
#define N3c 2304
#define Mc 4096
#define ROWSc (Bc * Hc * Lc)  // 49152

DEVI void glds16(const bf16_t* g, bf16_t* l) {
  __builtin_amdgcn_global_load_lds(
      (const __attribute__((address_space(1))) void*)g,
      (__attribute__((address_space(3))) void*)l, 16, 0, 0);
}

// ---------------- conversion kernels ----------------

__global__ __launch_bounds__(256) void k_cvt(const float* __restrict__ in,
                                             bf16_t* __restrict__ out, int n) {
  int i = (blockIdx.x * 256 + threadIdx.x) * 4;
  if (i >= n) return;
  float4 v = *(const float4*)(in + i);
  bf16x4 o;
  o[0] = (bf16_t)v.x; o[1] = (bf16_t)v.y; o[2] = (bf16_t)v.z; o[3] = (bf16_t)v.w;
  *(bf16x4*)(out + i) = o;
}

__global__ __launch_bounds__(256) void k_tc(const float* __restrict__ in,
                                            bf16_t* __restrict__ out, int R, int C) {
  __shared__ float tile[32][33];
  int c0 = blockIdx.x * 32, r0 = blockIdx.y * 32;
  int tx = threadIdx.x, ty = threadIdx.y;
  #pragma unroll
  for (int i = 0; i < 32; i += 8)
    tile[ty + i][tx] = in[(size_t)(r0 + ty + i) * C + c0 + tx];
  __syncthreads();
  #pragma unroll
  for (int i = 0; i < 32; i += 8)
    out[(size_t)(c0 + ty + i) * R + r0 + tx] = (bf16_t)tile[tx][ty + i];
}

// ---------------- GEMM core (m97 pattern) ----------------

DEVI void gemm_core(const bf16_t* __restrict__ A, const bf16_t* __restrict__ Bt,
                    bf16_t* lA, bf16_t* lB, int m0, int n0, floatx4 (&acc)[4][4]) {
  const int tid = threadIdx.x, wave = tid >> 6, lane = tid & 63;
  const int wm = (wave >> 1) * 64, wn = (wave & 1) * 64;
  const int lrow = lane >> 2, lseg = lane & 3;
  const int quad = lane >> 4, r16 = lane & 15;
  for (int kk = 0; kk < 768; kk += 32) {
    glds16(A  + (size_t)(m0 + wave * 32      + lrow) * 768 + kk + lseg * 8, lA + (wave * 32) * 32);
    glds16(A  + (size_t)(m0 + wave * 32 + 16 + lrow) * 768 + kk + lseg * 8, lA + (wave * 32 + 16) * 32);
    glds16(Bt + (size_t)(n0 + wave * 32      + lrow) * 768 + kk + lseg * 8, lB + (wave * 32) * 32);
    glds16(Bt + (size_t)(n0 + wave * 32 + 16 + lrow) * 768 + kk + lseg * 8, lB + (wave * 32 + 16) * 32);
    __syncthreads();
    bf16x8 af[4], bv[4];
    #pragma unroll
    for (int mi = 0; mi < 4; mi++)
      af[mi] = *(const bf16x8*)(lA + (wm + mi * 16 + r16) * 32 + quad * 8);
    #pragma unroll
    for (int ni = 0; ni < 4; ni++)
      bv[ni] = *(const bf16x8*)(lB + (wn + ni * 16 + r16) * 32 + quad * 8);
    #pragma unroll
    for (int mi = 0; mi < 4; mi++)
      #pragma unroll
      for (int ni = 0; ni < 4; ni++)
        acc[mi][ni] = __builtin_amdgcn_mfma_f32_16x16x32_bf16(af[mi], bv[ni], acc[mi][ni], 0, 0, 0);
    __syncthreads();
  }
}

__global__ __launch_bounds__(256) void k_gemm_qkv(
    const bf16_t* __restrict__ A, const bf16_t* __restrict__ Bt,
    const float* __restrict__ bias,
    bf16_t* __restrict__ Qo, bf16_t* __restrict__ Ko, bf16_t* __restrict__ Vo) {
  __shared__ bf16_t lA[128 * 32];
  __shared__ bf16_t lB[128 * 32];
  const int m0 = blockIdx.y * 128, n0 = blockIdx.x * 128;
  const int tid = threadIdx.x, wave = tid >> 6, lane = tid & 63;
  const int wm = (wave >> 1) * 64, wn = (wave & 1) * 64;
  const int quad = lane >> 4, r16 = lane & 15;
  floatx4 acc[4][4] = {};
  gemm_core(A, Bt, lA, lB, m0, n0, acc);

  const int sec = n0 / 768;
  bf16_t* dst = (sec == 0) ? Qo : ((sec == 1) ? Ko : Vo);
  #pragma unroll
  for (int ni = 0; ni < 4; ni++) {
    const int n = n0 + wn + ni * 16 + r16;
    const int nn = n - sec * 768;
    const int h = nn >> 6, d = nn & 63;
    const float bvs = bias[n];
    #pragma unroll
    for (int mi = 0; mi < 4; mi++) {
      #pragma unroll
      for (int reg = 0; reg < 4; reg++) {
        const int m = m0 + wm + mi * 16 + quad * 4 + reg;
        const int b = m >> 11, l = m & 2047;
        const float v = acc[mi][ni][reg] + bvs;
        dst[(((size_t)(b * Hc + h)) * Lc + l) * Dc + d] = (bf16_t)v;
      }
    }
  }
}

__global__ __launch_bounds__(256) void k_gemm_out(
    const bf16_t* __restrict__ A, const bf16_t* __restrict__ Bt,
    const float* __restrict__ bias, float* __restrict__ out) {
  __shared__ bf16_t lA[128 * 32];
  __shared__ bf16_t lB[128 * 32];
  const int m0 = blockIdx.y * 128, n0 = blockIdx.x * 128;
  const int tid = threadIdx.x, wave = tid >> 6, lane = tid & 63;
  const int wm = (wave >> 1) * 64, wn = (wave & 1) * 64;
  const int quad = lane >> 4, r16 = lane & 15;
  floatx4 acc[4][4] = {};
  gemm_core(A, Bt, lA, lB, m0, n0, acc);
  #pragma unroll
  for (int ni = 0; ni < 4; ni++) {
    const int n = n0 + wn + ni * 16 + r16;
    const float bvs = bias[n];
    #pragma unroll
    for (int mi = 0; mi < 4; mi++) {
      #pragma unroll
      for (int reg = 0; reg < 4; reg++) {
        const int m = m0 + wm + mi * 16 + quad * 4 + reg;
        out[(size_t)m * Ec + n] = acc[mi][ni][reg] + bvs;
      }
    }
  }
}

// ---------------- q_sq / k_sq (ksq carries +eps) + mask bias ----------------
__global__ __launch_bounds__(256) void k_sq(const bf16_t* __restrict__ Q,
                                            const bf16_t* __restrict__ K,
                                            const int* __restrict__ mask,
                                            float* __restrict__ qsq, float* __restrict__ ksq,
                                            float* __restrict__ mbias) {
  const int row = blockIdx.x * 256 + threadIdx.x;
  const bf16x8* q = (const bf16x8*)(Q + (size_t)row * 64);
  const bf16x8* k = (const bf16x8*)(K + (size_t)row * 64);
  float sq = 0.f, sk = 0.f;
  #pragma unroll
  for (int c = 0; c < 8; c++) {
    bf16x8 vq = q[c], vk = k[c];
    #pragma unroll
    for (int j = 0; j < 8; j++) {
      float a = (float)vq[j]; sq += a * a;
      float b = (float)vk[j]; sk += b * b;
    }
  }
  qsq[row] = sq;
  ksq[row] = sk + 1e-6f;
  const int bh = row >> 11, l = row & 2047;
  if (bh == 0 || bh == Hc) {  // one (b,*) representative per batch
    const int b = bh / Hc;
    mbias[b * Lc + l] = (mask[b * Lc + l] == 1) ? 0.f : -1e30f;
  }
}

// ---------------- V transpose ----------------
__global__ __launch_bounds__(256) void k_vt(const bf16_t* __restrict__ V,
                                            bf16_t* __restrict__ VT) {
  __shared__ bf16_t t[64][72];
  const int gid = blockIdx.x;
  const int bh = gid >> 5, j0 = (gid & 31) * 64;
  const int tid = threadIdx.x;
  const bf16_t* Vh = V + ((size_t)bh * Lc) * Dc;
  bf16_t* VTh = VT + ((size_t)bh * Dc) * Lc;
  #pragma unroll
  for (int it = 0; it < 2; ++it) {
    int c = tid + it * 256;
    int j = c >> 3, seg = c & 7;
    *(bf16x8*)&t[j][seg * 8] = *(const bf16x8*)(Vh + (size_t)(j0 + j) * 64 + seg * 8);
  }
  __syncthreads();
  #pragma unroll
  for (int it = 0; it < 2; ++it) {
    int c = tid + it * 256;
    int d = c >> 3, jseg = c & 7;
    bf16x8 o;
    #pragma unroll
    for (int u = 0; u < 8; u++) o[u] = t[jseg * 8 + u][d];
    *(bf16x8*)(VTh + (size_t)d * Lc + j0 + jseg * 8) = o;
  }
}

// ---------------- flash attention: direct-from-global fragments ----------------
// grid = (768, S). Block: 4 independent waves, 64 queries (wave = 16).
// K/VT fragments read straight from global (L2-resident; XCD swizzle keeps
// 3 bh per XCD). Only LDS use: per-wave P round-trip. ZERO barriers.
// S^T = K.Q^T scores; O^T = VT.P^T -> softmax state per-lane (query = r16).
__global__ __launch_bounds__(256) void k_attn(
    const bf16_t* __restrict__ Q, const bf16_t* __restrict__ K,
    const bf16_t* __restrict__ VT, const float* __restrict__ qsq,
    const float* __restrict__ ksq, const float* __restrict__ mbias,
    float* __restrict__ Op, float* __restrict__ Mp, float* __restrict__ Lp,
    int nS) {
  __shared__ bf16_t lP[4][16 * 72];
  const int gid0 = blockIdx.x;
  const int gid = (gid0 & 7) * 96 + (gid0 >> 3);  // XCD swizzle: 96 blocks = 3 bh per XCD
  const int s = blockIdx.y;
  const int bh = gid >> 5, qt = gid & 31;
  const int b = bh / Hc;
  const int tid = threadIdx.x, wave = tid >> 6, lane = tid & 63;
  const int quad = lane >> 4, r16 = lane & 15;
  const int q0 = qt * 64 + wave * 16;
  const bf16_t* Qh = Q + ((size_t)bh * Lc) * Dc;
  const bf16_t* Kh = K + ((size_t)bh * Lc) * Dc;
  const bf16_t* VTh = VT + ((size_t)bh * Dc) * Lc;
  const float* ksqh = ksq + bh * Lc;
  const float* mbb = mbias + b * Lc;
  bf16_t* myP = &lP[wave][0];

  const int kt_lo = (32 * s) / nS * 64;
  const int kt_hi = (32 * (s + 1)) / nS * 64;
  const int nt = (kt_hi - kt_lo) >> 6;

  // Q B-fragments + per-lane query state
  bf16x8 qf0 = *(const bf16x8*)(Qh + (size_t)(q0 + r16) * 64 + quad * 8);
  bf16x8 qf1 = *(const bf16x8*)(Qh + (size_t)(q0 + r16) * 64 + 32 + quad * 8);
  const float qs = qsq[bh * Lc + q0 + r16];
  float mi = -1e30f, li = 0.f;
  floatx4 of[4] = {};  // O^T: lane holds O^T[d=t4*16+quad*4+reg][q=r16]

  // direct-fragment base pointers (A-operand rows: 16 rows x 64B segments)
  const bf16_t* kb = Kh + (size_t)r16 * 64 + quad * 8;   // + (kt + c*16)*64
  const bf16_t* vb = VTh + (size_t)r16 * Lc + quad * 8;  // + t4*16*Lc + kt

  for (int t = 0; t < nt; t++) {
    const int kt = kt_lo + t * 64;
    // ksq/mask-bias for this lane's 16 keys (c*16 + quad*4 + reg)
    float4 ks4[4], mb4[4];
    #pragma unroll
    for (int c = 0; c < 4; c++) {
      ks4[c] = *(const float4*)(ksqh + kt + c * 16 + quad * 4);
      mb4[c] = *(const float4*)(mbb + kt + c * 16 + quad * 4);
    }
    // S^T MFMAs, K fragments direct from global
    floatx4 dot[4];
    #pragma unroll
    for (int c = 0; c < 4; c++) {
      const bf16_t* kr = kb + (size_t)(kt + c * 16) * 64;
      bf16x8 kf0 = *(const bf16x8*)kr;
      bf16x8 kf1 = *(const bf16x8*)(kr + 32);
      floatx4 a = {};
      a = __builtin_amdgcn_mfma_f32_16x16x32_bf16(kf0, qf0, a, 0, 0, 0);
      a = __builtin_amdgcn_mfma_f32_16x16x32_bf16(kf1, qf1, a, 0, 0, 0);
      dot[c] = a;
    }
    // transform + online softmax (lane owns 16 scores of query r16)
    float sv[4][4];
    float rmax = -1e30f;
    #pragma unroll
    for (int c = 0; c < 4; c++) {
      #pragma unroll
      for (int reg = 0; reg < 4; reg++) {
        const float dd = dot[c][reg];
        const float kss = ((const float*)&ks4[c])[reg];  // has +eps
        const float mbv = ((const float*)&mb4[c])[reg];  // 0 or -1e30
        const float den = qs + kss - 2.f * dd;
        const float sc = dd * dd * __builtin_amdgcn_rcpf(den) + mbv;
        sv[c][reg] = sc;
        rmax = fmaxf(rmax, sc);
      }
    }
    rmax = fmaxf(rmax, __shfl_xor(rmax, 16));
    rmax = fmaxf(rmax, __shfl_xor(rmax, 32));
    const float mnew = fmaxf(mi, rmax);
    const float alpha = __expf(mi - mnew);
    float psum = 0.f;
    #pragma unroll
    for (int c = 0; c < 4; c++) {
      bf16x4 pk;
      #pragma unroll
      for (int reg = 0; reg < 4; reg++) {
        const float p = __expf(sv[c][reg] - mnew);  // masked: exp(-huge)=0
        psum += p;
        pk[reg] = (bf16_t)p;
      }
      *(bf16x4*)(myP + r16 * 72 + c * 16 + quad * 4) = pk;
    }
    // issue V fragment loads now; latency hides under psum/rescale VALU
    bf16x8 vf0[4], vf1[4];
    #pragma unroll
    for (int t4 = 0; t4 < 4; t4++) {
      const bf16_t* vr = vb + (size_t)(t4 * 16) * Lc + kt;
      vf0[t4] = *(const bf16x8*)vr;
      vf1[t4] = *(const bf16x8*)(vr + 32);
    }
    psum += __shfl_xor(psum, 16);
    psum += __shfl_xor(psum, 32);
    li = li * alpha + psum;
    mi = mnew;
    #pragma unroll
    for (int t4 = 0; t4 < 4; t4++) {
      #pragma unroll
      for (int reg = 0; reg < 4; reg++) of[t4][reg] *= alpha;
    }
    // O^T += VT . P^T : A = VT frag (m=d), B = P frag (n=query)
    bf16x8 pf0 = *(const bf16x8*)(myP + r16 * 72 + quad * 8);
    bf16x8 pf1 = *(const bf16x8*)(myP + r16 * 72 + 32 + quad * 8);
    #pragma unroll
    for (int t4 = 0; t4 < 4; t4++) {
      of[t4] = __builtin_amdgcn_mfma_f32_16x16x32_bf16(vf0[t4], pf0, of[t4], 0, 0, 0);
      of[t4] = __builtin_amdgcn_mfma_f32_16x16x32_bf16(vf1[t4], pf1, of[t4], 0, 0, 0);
    }
  }
  // epilogue: lane writes O^T[d][q=r16] -> Op[idx(q)*64 + d], d = t4*16+quad*4+reg
  const size_t idx = (size_t)s * ROWSc + (size_t)bh * Lc + q0 + r16;
  #pragma unroll
  for (int t4 = 0; t4 < 4; t4++)
    *(float4*)(Op + idx * 64 + t4 * 16 + quad * 4) =
        make_float4(of[t4][0], of[t4][1], of[t4][2], of[t4][3]);
  if (lane < 16) { Mp[idx] = mi; Lp[idx] = li; }
}

// ---------------- merge partials -> AO ----------------
__global__ __launch_bounds__(256) void k_merge(
    const float* __restrict__ Op, const float* __restrict__ Mp,
    const float* __restrict__ Lp, bf16_t* __restrict__ AO, int nS) {
  const int t = blockIdx.x * 256 + threadIdx.x;
  const int row = t >> 4, dc = (t & 15) * 4;
  float mmax = -1e30f;
  for (int s = 0; s < nS; s++) mmax = fmaxf(mmax, Mp[(size_t)s * ROWSc + row]);
  float L = 0.f;
  float o0 = 0.f, o1 = 0.f, o2 = 0.f, o3 = 0.f;
  for (int s = 0; s < nS; s++) {
    const size_t idx = (size_t)s * ROWSc + row;
    const float w = __expf(Mp[idx] - mmax);
    L += w * Lp[idx];
    const float4 v = *(const float4*)(Op + idx * 64 + dc);
    o0 += w * v.x; o1 += w * v.y; o2 += w * v.z; o3 += w * v.w;
  }
  const float inv = (L > 0.f) ? __builtin_amdgcn_rcpf(L) : 0.f;
  const int bh = row >> 11, l = row & 2047;
  const int b = bh / Hc, h = bh - b * Hc;
  bf16x4 o;
  o[0] = (bf16_t)(o0 * inv); o[1] = (bf16_t)(o1 * inv);
  o[2] = (bf16_t)(o2 * inv); o[3] = (bf16_t)(o3 * inv);
  *(bf16x4*)(AO + ((size_t)(b * Lc + l)) * Ec + h * 64 + dc) = o;
}

// ---------------- launch ----------------

extern "C" void kernel_launch(void* const* d_in, const int* in_sizes, int n_in,
                              void* d_out, int out_size, void* d_ws, size_t ws_size,
                              hipStream_t stream) {
  const float* x    = (const float*)d_in[0];
  const int*   mask = (const int*)d_in[1];
  const float* Wqkv = (const float*)d_in[2];
  const float* bqkv = (const float*)d_in[3];
  const float* Wout = (const float*)d_in[4];
  const float* bout = (const float*)d_in[5];
  float* out = (float*)d_out;

  auto al = [](size_t x) { return (x + 255) & ~(size_t)255; };
  char* ws = (char*)d_ws;
  size_t off = 0;
  auto carve = [&](size_t bytes) -> char* {
    char* p = ws + off;
    off += al(bytes);
    return p;
  };
  bf16_t* WoT = (bf16_t*)carve((size_t)Ec * Ec * 2);
  bf16_t* Qb  = (bf16_t*)carve((size_t)ROWSc * Dc * 2);
  bf16_t* Kb  = (bf16_t*)carve((size_t)ROWSc * Dc * 2);
  bf16_t* VTb = (bf16_t*)carve((size_t)ROWSc * Dc * 2);
  bf16_t* AOb = (bf16_t*)carve((size_t)Mc * Ec * 2);
  float*  qsq = (float*)carve((size_t)ROWSc * 4);
  float*  ksq = (float*)carve((size_t)ROWSc * 4);
  float*  mbias = (float*)carve((size_t)Bc * Lc * 4);
  const size_t uni = off;
  bf16_t* xb  = (bf16_t*)(ws + uni);
  bf16_t* WqT = (bf16_t*)(ws + uni + al((size_t)Mc * Ec * 2));
  bf16_t* Vb  = (bf16_t*)(ws + uni + al((size_t)Mc * Ec * 2) + al((size_t)N3c * Ec * 2));
  const size_t ph1 = al((size_t)Mc * Ec * 2) + al((size_t)N3c * Ec * 2) + al((size_t)ROWSc * Dc * 2);
  auto ph2 = [&](int S) {
    return al((size_t)S * ROWSc * Dc * 4) + 2 * al((size_t)S * ROWSc * 4);
  };
  int S = 1;
  {
    size_t need = uni + (ph1 > ph2(2) ? ph1 : ph2(2));
    if (need <= ws_size) S = 2;
  }
  float* Op = (float*)(ws + uni);
  float* Mp = (float*)(ws + uni + al((size_t)S * ROWSc * Dc * 4));
  float* Lp = (float*)(ws + uni + al((size_t)S * ROWSc * Dc * 4) + al((size_t)S * ROWSc * 4));
  (void)in_sizes; (void)n_in; (void)out_size;

  k_cvt<<<(Mc * Ec / 4 + 255) / 256, 256, 0, stream>>>(x, xb, Mc * Ec);
  k_tc<<<dim3(N3c / 32, Ec / 32), dim3(32, 8), 0, stream>>>(Wqkv, WqT, Ec, N3c);
  k_tc<<<dim3(Ec / 32, Ec / 32), dim3(32, 8), 0, stream>>>(Wout, WoT, Ec, Ec);
  k_gemm_qkv<<<dim3(N3c / 128, Mc / 128), 256, 0, stream>>>(xb, WqT, bqkv, Qb, Kb, Vb);
  k_sq<<<ROWSc / 256, 256, 0, stream>>>(Qb, Kb, mask, qsq, ksq, mbias);
  k_vt<<<ROWSc / 64, 256, 0, stream>>>(Vb, VTb);
  k_attn<<<dim3(ROWSc / 64, S), 256, 0, stream>>>(Qb, Kb, VTb, qsq, ksq, mbias, Op, Mp, Lp, S);
  k_merge<<<ROWSc * 16 / 256, 256, 0, stream>>>(Op, Mp, Lp, AOb, S);
  k_gemm_out<<<dim3(Ec / 128, Mc / 128), 256, 0, stream>>>(AOb, WoT, bout, out);
}

// Round 3
// 272.166 us; speedup vs baseline: 1.2980x; 1.2980x over previous
//
#include <hip/hip_runtime.h>
#include <hip/hip_bf16.h>
#include <cstdint>
#include <cstddef>

// YatAttention on MI355X (gfx950).
// B=2, L=2048, E=768, H=12, D=64. GEMMs in bf16 MFMA 16x16x32 (fp32 accum).
// R6b: hybrid attn staging (R6 + compile fix). R5 post-mortem: direct-global
// K fragments stall (consumed immediately, ~200cy L2 latency, VALUBusy
// 62->20%). So K stays LDS-staged (glds16 dbuf = full-tile prefetch cover,
// as R4); V moves to direct-global register fragments issued at TILE TOP --
// consumed only after QK^T + full softmax transform (~400cy cover). V loads
// issue BEFORE the K glds prefetch so vmcnt waits on V don't drain K staging.
// LDS 41984 -> 25600 B (drop V dbuf) -> 6 blocks/CU by LDS; occupancy cap
// moves to VGPR band. Keeps R5's mbias fold + XCD swizzle (verified).

typedef __bf16 bf16_t;
typedef __bf16 bf16x8 __attribute__((ext_vector_type(8)));
typedef __bf16 bf16x4 __attribute__((ext_vector_type(4)));
typedef float floatx4 __attribute__((ext_vector_type(4)));

#define DEVI static __device__ __forceinline__

#define Bc 2
#define Lc 2048
#define Ec 768
#define Hc 12
#define Dc 64
#define N3c 2304
#define Mc 4096
#define ROWSc (Bc * Hc * Lc)  // 49152

DEVI void glds16(const bf16_t* g, bf16_t* l) {
  __builtin_amdgcn_global_load_lds(
      (const __attribute__((address_space(1))) void*)g,
      (__attribute__((address_space(3))) void*)l, 16, 0, 0);
}

// ---------------- conversion kernels ----------------

__global__ __launch_bounds__(256) void k_cvt(const float* __restrict__ in,
                                             bf16_t* __restrict__ out, int n) {
  int i = (blockIdx.x * 256 + threadIdx.x) * 4;
  if (i >= n) return;
  float4 v = *(const float4*)(in + i);
  bf16x4 o;
  o[0] = (bf16_t)v.x; o[1] = (bf16_t)v.y; o[2] = (bf16_t)v.z; o[3] = (bf16_t)v.w;
  *(bf16x4*)(out + i) = o;
}

__global__ __launch_bounds__(256) void k_tc(const float* __restrict__ in,
                                            bf16_t* __restrict__ out, int R, int C) {
  __shared__ float tile[32][33];
  int c0 = blockIdx.x * 32, r0 = blockIdx.y * 32;
  int tx = threadIdx.x, ty = threadIdx.y;
  #pragma unroll
  for (int i = 0; i < 32; i += 8)
    tile[ty + i][tx] = in[(size_t)(r0 + ty + i) * C + c0 + tx];
  __syncthreads();
  #pragma unroll
  for (int i = 0; i < 32; i += 8)
    out[(size_t)(c0 + ty + i) * R + r0 + tx] = (bf16_t)tile[tx][ty + i];
}

// ---------------- GEMM core (m97 pattern) ----------------

DEVI void gemm_core(const bf16_t* __restrict__ A, const bf16_t* __restrict__ Bt,
                    bf16_t* lA, bf16_t* lB, int m0, int n0, floatx4 (&acc)[4][4]) {
  const int tid = threadIdx.x, wave = tid >> 6, lane = tid & 63;
  const int wm = (wave >> 1) * 64, wn = (wave & 1) * 64;
  const int lrow = lane >> 2, lseg = lane & 3;
  const int quad = lane >> 4, r16 = lane & 15;
  for (int kk = 0; kk < 768; kk += 32) {
    glds16(A  + (size_t)(m0 + wave * 32      + lrow) * 768 + kk + lseg * 8, lA + (wave * 32) * 32);
    glds16(A  + (size_t)(m0 + wave * 32 + 16 + lrow) * 768 + kk + lseg * 8, lA + (wave * 32 + 16) * 32);
    glds16(Bt + (size_t)(n0 + wave * 32      + lrow) * 768 + kk + lseg * 8, lB + (wave * 32) * 32);
    glds16(Bt + (size_t)(n0 + wave * 32 + 16 + lrow) * 768 + kk + lseg * 8, lB + (wave * 32 + 16) * 32);
    __syncthreads();
    bf16x8 af[4], bv[4];
    #pragma unroll
    for (int mi = 0; mi < 4; mi++)
      af[mi] = *(const bf16x8*)(lA + (wm + mi * 16 + r16) * 32 + quad * 8);
    #pragma unroll
    for (int ni = 0; ni < 4; ni++)
      bv[ni] = *(const bf16x8*)(lB + (wn + ni * 16 + r16) * 32 + quad * 8);
    #pragma unroll
    for (int mi = 0; mi < 4; mi++)
      #pragma unroll
      for (int ni = 0; ni < 4; ni++)
        acc[mi][ni] = __builtin_amdgcn_mfma_f32_16x16x32_bf16(af[mi], bv[ni], acc[mi][ni], 0, 0, 0);
    __syncthreads();
  }
}

__global__ __launch_bounds__(256) void k_gemm_qkv(
    const bf16_t* __restrict__ A, const bf16_t* __restrict__ Bt,
    const float* __restrict__ bias,
    bf16_t* __restrict__ Qo, bf16_t* __restrict__ Ko, bf16_t* __restrict__ Vo) {
  __shared__ bf16_t lA[128 * 32];
  __shared__ bf16_t lB[128 * 32];
  const int m0 = blockIdx.y * 128, n0 = blockIdx.x * 128;
  const int tid = threadIdx.x, wave = tid >> 6, lane = tid & 63;
  const int wm = (wave >> 1) * 64, wn = (wave & 1) * 64;
  const int quad = lane >> 4, r16 = lane & 15;
  floatx4 acc[4][4] = {};
  gemm_core(A, Bt, lA, lB, m0, n0, acc);

  const int sec = n0 / 768;
  bf16_t* dst = (sec == 0) ? Qo : ((sec == 1) ? Ko : Vo);
  #pragma unroll
  for (int ni = 0; ni < 4; ni++) {
    const int n = n0 + wn + ni * 16 + r16;
    const int nn = n - sec * 768;
    const int h = nn >> 6, d = nn & 63;
    const float bvs = bias[n];
    #pragma unroll
    for (int mi = 0; mi < 4; mi++) {
      #pragma unroll
      for (int reg = 0; reg < 4; reg++) {
        const int m = m0 + wm + mi * 16 + quad * 4 + reg;
        const int b = m >> 11, l = m & 2047;
        const float v = acc[mi][ni][reg] + bvs;
        dst[(((size_t)(b * Hc + h)) * Lc + l) * Dc + d] = (bf16_t)v;
      }
    }
  }
}

__global__ __launch_bounds__(256) void k_gemm_out(
    const bf16_t* __restrict__ A, const bf16_t* __restrict__ Bt,
    const float* __restrict__ bias, float* __restrict__ out) {
  __shared__ bf16_t lA[128 * 32];
  __shared__ bf16_t lB[128 * 32];
  const int m0 = blockIdx.y * 128, n0 = blockIdx.x * 128;
  const int tid = threadIdx.x, wave = tid >> 6, lane = tid & 63;
  const int wm = (wave >> 1) * 64, wn = (wave & 1) * 64;
  const int quad = lane >> 4, r16 = lane & 15;
  floatx4 acc[4][4] = {};
  gemm_core(A, Bt, lA, lB, m0, n0, acc);
  #pragma unroll
  for (int ni = 0; ni < 4; ni++) {
    const int n = n0 + wn + ni * 16 + r16;
    const float bvs = bias[n];
    #pragma unroll
    for (int mi = 0; mi < 4; mi++) {
      #pragma unroll
      for (int reg = 0; reg < 4; reg++) {
        const int m = m0 + wm + mi * 16 + quad * 4 + reg;
        out[(size_t)m * Ec + n] = acc[mi][ni][reg] + bvs;
      }
    }
  }
}

// ---------------- q_sq / k_sq (ksq carries +eps) + mask bias ----------------
__global__ __launch_bounds__(256) void k_sq(const bf16_t* __restrict__ Q,
                                            const bf16_t* __restrict__ K,
                                            const int* __restrict__ mask,
                                            float* __restrict__ qsq, float* __restrict__ ksq,
                                            float* __restrict__ mbias) {
  const int row = blockIdx.x * 256 + threadIdx.x;
  const bf16x8* q = (const bf16x8*)(Q + (size_t)row * 64);
  const bf16x8* k = (const bf16x8*)(K + (size_t)row * 64);
  float sq = 0.f, sk = 0.f;
  #pragma unroll
  for (int c = 0; c < 8; c++) {
    bf16x8 vq = q[c], vk = k[c];
    #pragma unroll
    for (int j = 0; j < 8; j++) {
      float a = (float)vq[j]; sq += a * a;
      float b = (float)vk[j]; sk += b * b;
    }
  }
  qsq[row] = sq;
  ksq[row] = sk + 1e-6f;
  const int bh = row >> 11, l = row & 2047;
  if (bh == 0 || bh == Hc) {  // one (b,*) representative per batch
    const int b = bh / Hc;
    mbias[b * Lc + l] = (mask[b * Lc + l] == 1) ? 0.f : -1e30f;
  }
}

// ---------------- V transpose ----------------
__global__ __launch_bounds__(256) void k_vt(const bf16_t* __restrict__ V,
                                            bf16_t* __restrict__ VT) {
  __shared__ bf16_t t[64][72];
  const int gid = blockIdx.x;
  const int bh = gid >> 5, j0 = (gid & 31) * 64;
  const int tid = threadIdx.x;
  const bf16_t* Vh = V + ((size_t)bh * Lc) * Dc;
  bf16_t* VTh = VT + ((size_t)bh * Dc) * Lc;
  #pragma unroll
  for (int it = 0; it < 2; ++it) {
    int c = tid + it * 256;
    int j = c >> 3, seg = c & 7;
    *(bf16x8*)&t[j][seg * 8] = *(const bf16x8*)(Vh + (size_t)(j0 + j) * 64 + seg * 8);
  }
  __syncthreads();
  #pragma unroll
  for (int it = 0; it < 2; ++it) {
    int c = tid + it * 256;
    int d = c >> 3, jseg = c & 7;
    bf16x8 o;
    #pragma unroll
    for (int u = 0; u < 8; u++) o[u] = t[jseg * 8 + u][d];
    *(bf16x8*)(VTh + (size_t)d * Lc + j0 + jseg * 8) = o;
  }
}

// ---------------- flash attention: K LDS-staged, V direct w/ early issue ----
// grid = (768, S). Block: 4 waves, 64 queries (wave = 16). Key tile = 64.
// K tile staged via glds16 dbuf (one-tile-ahead prefetch cover). V fragments
// loaded direct global -> regs at TILE TOP, consumed after full softmax
// (~400cy cover). One barrier per tile. S^T = K.Q^T; O^T = VT.P^T so all
// softmax state is per-lane (query = r16).
__global__ __launch_bounds__(256) void k_attn(
    const bf16_t* __restrict__ Q, const bf16_t* __restrict__ K,
    const bf16_t* __restrict__ VT, const float* __restrict__ qsq,
    const float* __restrict__ ksq, const float* __restrict__ mbias,
    float* __restrict__ Op, float* __restrict__ Mp, float* __restrict__ Lp,
    int nS) {
  __shared__ bf16_t lK[2][4096];   // 64 keys x 64 d, swizzled 16B chunks
  __shared__ bf16_t lP[4][16 * 72];
  const int gid0 = blockIdx.x;
  const int gid = (gid0 & 7) * 96 + (gid0 >> 3);  // XCD swizzle: 3 bh per XCD
  const int s = blockIdx.y;
  const int bh = gid >> 5, qt = gid & 31;
  const int b = bh / Hc;
  const int tid = threadIdx.x, wave = tid >> 6, lane = tid & 63;
  const int quad = lane >> 4, r16 = lane & 15;
  const int q0 = qt * 64 + wave * 16;
  const bf16_t* Qh = Q + ((size_t)bh * Lc) * Dc;
  const bf16_t* Kh = K + ((size_t)bh * Lc) * Dc;
  const bf16_t* VTh = VT + ((size_t)bh * Dc) * Lc;
  const float* qsqh = qsq + bh * Lc;
  const float* ksqh = ksq + bh * Lc;
  const float* mbb = mbias + b * Lc;
  bf16_t* myP = &lP[wave][0];

  const int kt_lo = (32 * s) / nS * 64;
  const int kt_hi = (32 * (s + 1)) / nS * 64;
  const int nt = (kt_hi - kt_lo) >> 6;

  // --- K staging geometry: chunk p = i*256 + wave*64 + lane covers row p>>3,
  // slot p&7 which holds global chunk (p&7)^((p>>3)&7).
  const int p0 = wave * 64 + lane;         // inst 0; inst 1 = p0 + 256 (row+32)
  const int srow = p0 >> 3;                // 0..31
  const int sj = (p0 & 7) ^ (srow & 7);    // swizzled global chunk
  const bf16_t* kg0 = Kh + (size_t)(kt_lo + srow) * 64 + sj * 8;
  const bf16_t* kg1 = kg0 + 32 * 64;
  // LDS dests (wave-uniform): chunk base (i*256 + wave*64)*8 elements
  const int ld0 = wave * 64 * 8, ld1 = (256 + wave * 64) * 8;

  // fragment read offsets (swizzled slots), elements
  const int sl0 = ((quad ^ (r16 & 7)) * 8);
  const int sl1 = sl0 ^ 32;  // chunk quad+4

  // Q B-fragments + per-lane query state
  bf16x8 qf0 = *(const bf16x8*)(Qh + (size_t)(q0 + r16) * 64 + quad * 8);
  bf16x8 qf1 = *(const bf16x8*)(Qh + (size_t)(q0 + r16) * 64 + 32 + quad * 8);
  const float qs = qsqh[q0 + r16];
  float mi = -1e30f, li = 0.f;
  floatx4 of[4] = {};  // O^T: lane holds O^T[d=t4*16+quad*4+reg][q=r16]

  // V direct-fragment base (A-operand rows: d = t4*16 + r16)
  const bf16_t* vb = VTh + (size_t)r16 * Lc + quad * 8;  // + t4*16*Lc + kt

  // prologue: stage K tile 0 into buf 0
  glds16(kg0, &lK[0][ld0]);
  glds16(kg1, &lK[0][ld1]);
  kg0 += 4096; kg1 += 4096;
  __syncthreads();

  for (int t = 0; t < nt; t++) {
    const int cur = t & 1;
    const int kt = kt_lo + t * 64;
    // V fragments for THIS tile: issue first (oldest vmcnt), consumed after
    // softmax -- QK^T + transform + exp chain is the latency cover.
    bf16x8 vf0[4], vf1[4];
    #pragma unroll
    for (int t4 = 0; t4 < 4; t4++) {
      const bf16_t* vr = vb + (size_t)(t4 * 16) * Lc + kt;
      vf0[t4] = *(const bf16x8*)vr;
      vf1[t4] = *(const bf16x8*)(vr + 32);
    }
    // ksq/mask-bias for this lane's 16 keys (c*16 + quad*4 + reg)
    float4 ks4[4], mb4[4];
    #pragma unroll
    for (int c = 0; c < 4; c++) {
      ks4[c] = *(const float4*)(ksqh + kt + c * 16 + quad * 4);
      mb4[c] = *(const float4*)(mbb + kt + c * 16 + quad * 4);
    }
    // K prefetch for next tile (younger than vf: vmcnt waits on vf won't
    // drain these)
    if (t + 1 < nt) {
      glds16(kg0, &lK[cur ^ 1][ld0]);
      glds16(kg1, &lK[cur ^ 1][ld1]);
      kg0 += 4096; kg1 += 4096;
    }
    // S^T MFMAs from LDS K tile
    floatx4 dot[4];
    #pragma unroll
    for (int c = 0; c < 4; c++) {
      const int rbase = (c * 16 + r16) * 64;
      bf16x8 kf0 = *(const bf16x8*)(&lK[cur][rbase + sl0]);
      bf16x8 kf1 = *(const bf16x8*)(&lK[cur][rbase + sl1]);
      floatx4 a = {};
      a = __builtin_amdgcn_mfma_f32_16x16x32_bf16(kf0, qf0, a, 0, 0, 0);
      a = __builtin_amdgcn_mfma_f32_16x16x32_bf16(kf1, qf1, a, 0, 0, 0);
      dot[c] = a;
    }
    // transform + online softmax (lane owns 16 scores of query r16);
    // scores overwrite dot[] to hold VGPR pressure down.
    float rmax = -1e30f;
    #pragma unroll
    for (int c = 0; c < 4; c++) {
      #pragma unroll
      for (int reg = 0; reg < 4; reg++) {
        const float dd = dot[c][reg];
        const float kss = ((const float*)&ks4[c])[reg];  // has +eps
        const float mbv = ((const float*)&mb4[c])[reg];  // 0 or -1e30
        const float den = qs + kss - 2.f * dd;
        const float sc = dd * dd * __builtin_amdgcn_rcpf(den) + mbv;
        dot[c][reg] = sc;
        rmax = fmaxf(rmax, sc);
      }
    }
    rmax = fmaxf(rmax, __shfl_xor(rmax, 16));
    rmax = fmaxf(rmax, __shfl_xor(rmax, 32));
    const float mnew = fmaxf(mi, rmax);
    const float alpha = __expf(mi - mnew);
    float psum = 0.f;
    #pragma unroll
    for (int c = 0; c < 4; c++) {
      bf16x4 pk;
      #pragma unroll
      for (int reg = 0; reg < 4; reg++) {
        const float p = __expf(dot[c][reg] - mnew);  // masked: exp(-huge)=0
        psum += p;
        pk[reg] = (bf16_t)p;
      }
      *(bf16x4*)(myP + r16 * 72 + c * 16 + quad * 4) = pk;
    }
    psum += __shfl_xor(psum, 16);
    psum += __shfl_xor(psum, 32);
    li = li * alpha + psum;
    mi = mnew;
    #pragma unroll
    for (int t4 = 0; t4 < 4; t4++) {
      #pragma unroll
      for (int reg = 0; reg < 4; reg++) of[t4][reg] *= alpha;
    }
    // O^T += VT . P^T : A = V frag (regs, m=d), B = P frag (n=query)
    bf16x8 pf0 = *(const bf16x8*)(myP + r16 * 72 + quad * 8);
    bf16x8 pf1 = *(const bf16x8*)(myP + r16 * 72 + 32 + quad * 8);
    #pragma unroll
    for (int t4 = 0; t4 < 4; t4++) {
      of[t4] = __builtin_amdgcn_mfma_f32_16x16x32_bf16(vf0[t4], pf0, of[t4], 0, 0, 0);
      of[t4] = __builtin_amdgcn_mfma_f32_16x16x32_bf16(vf1[t4], pf1, of[t4], 0, 0, 0);
    }
    __syncthreads();
  }
  // epilogue: lane writes O^T[d][q=r16] -> Op[idx(q)*64 + d], d = t4*16+quad*4+reg
  const size_t idx = (size_t)s * ROWSc + (size_t)bh * Lc + q0 + r16;
  #pragma unroll
  for (int t4 = 0; t4 < 4; t4++)
    *(float4*)(Op + idx * 64 + t4 * 16 + quad * 4) =
        make_float4(of[t4][0], of[t4][1], of[t4][2], of[t4][3]);
  if (lane < 16) { Mp[idx] = mi; Lp[idx] = li; }
}

// ---------------- merge partials -> AO ----------------
__global__ __launch_bounds__(256) void k_merge(
    const float* __restrict__ Op, const float* __restrict__ Mp,
    const float* __restrict__ Lp, bf16_t* __restrict__ AO, int nS) {
  const int t = blockIdx.x * 256 + threadIdx.x;
  const int row = t >> 4, dc = (t & 15) * 4;
  float mmax = -1e30f;
  for (int s = 0; s < nS; s++) mmax = fmaxf(mmax, Mp[(size_t)s * ROWSc + row]);
  float L = 0.f;
  float o0 = 0.f, o1 = 0.f, o2 = 0.f, o3 = 0.f;
  for (int s = 0; s < nS; s++) {
    const size_t idx = (size_t)s * ROWSc + row;
    const float w = __expf(Mp[idx] - mmax);
    L += w * Lp[idx];
    const float4 v = *(const float4*)(Op + idx * 64 + dc);
    o0 += w * v.x; o1 += w * v.y; o2 += w * v.z; o3 += w * v.w;
  }
  const float inv = (L > 0.f) ? __builtin_amdgcn_rcpf(L) : 0.f;
  const int bh = row >> 11, l = row & 2047;
  const int b = bh / Hc, h = bh - b * Hc;
  bf16x4 o;
  o[0] = (bf16_t)(o0 * inv); o[1] = (bf16_t)(o1 * inv);
  o[2] = (bf16_t)(o2 * inv); o[3] = (bf16_t)(o3 * inv);
  *(bf16x4*)(AO + ((size_t)(b * Lc + l)) * Ec + h * 64 + dc) = o;
}

// ---------------- launch ----------------

extern "C" void kernel_launch(void* const* d_in, const int* in_sizes, int n_in,
                              void* d_out, int out_size, void* d_ws, size_t ws_size,
                              hipStream_t stream) {
  const float* x    = (const float*)d_in[0];
  const int*   mask = (const int*)d_in[1];
  const float* Wqkv = (const float*)d_in[2];
  const float* bqkv = (const float*)d_in[3];
  const float* Wout = (const float*)d_in[4];
  const float* bout = (const float*)d_in[5];
  float* out = (float*)d_out;

  auto al = [](size_t x) { return (x + 255) & ~(size_t)255; };
  char* ws = (char*)d_ws;
  size_t off = 0;
  auto carve = [&](size_t bytes) -> char* {
    char* p = ws + off;
    off += al(bytes);
    return p;
  };
  bf16_t* WoT = (bf16_t*)carve((size_t)Ec * Ec * 2);
  bf16_t* Qb  = (bf16_t*)carve((size_t)ROWSc * Dc * 2);
  bf16_t* Kb  = (bf16_t*)carve((size_t)ROWSc * Dc * 2);
  bf16_t* VTb = (bf16_t*)carve((size_t)ROWSc * Dc * 2);
  bf16_t* AOb = (bf16_t*)carve((size_t)Mc * Ec * 2);
  float*  qsq = (float*)carve((size_t)ROWSc * 4);
  float*  ksq = (float*)carve((size_t)ROWSc * 4);
  float*  mbias = (float*)carve((size_t)Bc * Lc * 4);
  const size_t uni = off;
  bf16_t* xb  = (bf16_t*)(ws + uni);
  bf16_t* WqT = (bf16_t*)(ws + uni + al((size_t)Mc * Ec * 2));
  bf16_t* Vb  = (bf16_t*)(ws + uni + al((size_t)Mc * Ec * 2) + al((size_t)N3c * Ec * 2));
  const size_t ph1 = al((size_t)Mc * Ec * 2) + al((size_t)N3c * Ec * 2) + al((size_t)ROWSc * Dc * 2);
  auto ph2 = [&](int S) {
    return al((size_t)S * ROWSc * Dc * 4) + 2 * al((size_t)S * ROWSc * 4);
  };
  int S = 1;
  {
    size_t need = uni + (ph1 > ph2(2) ? ph1 : ph2(2));
    if (need <= ws_size) S = 2;
  }
  float* Op = (float*)(ws + uni);
  float* Mp = (float*)(ws + uni + al((size_t)S * ROWSc * Dc * 4));
  float* Lp = (float*)(ws + uni + al((size_t)S * ROWSc * Dc * 4) + al((size_t)S * ROWSc * 4));
  (void)in_sizes; (void)n_in; (void)out_size;

  k_cvt<<<(Mc * Ec / 4 + 255) / 256, 256, 0, stream>>>(x, xb, Mc * Ec);
  k_tc<<<dim3(N3c / 32, Ec / 32), dim3(32, 8), 0, stream>>>(Wqkv, WqT, Ec, N3c);
  k_tc<<<dim3(Ec / 32, Ec / 32), dim3(32, 8), 0, stream>>>(Wout, WoT, Ec, Ec);
  k_gemm_qkv<<<dim3(N3c / 128, Mc / 128), 256, 0, stream>>>(xb, WqT, bqkv, Qb, Kb, Vb);
  k_sq<<<ROWSc / 256, 256, 0, stream>>>(Qb, Kb, mask, qsq, ksq, mbias);
  k_vt<<<ROWSc / 64, 256, 0, stream>>>(Vb, VTb);
  k_attn<<<dim3(ROWSc / 64, S), 256, 0, stream>>>(Qb, Kb, VTb, qsq, ksq, mbias, Op, Mp, Lp, S);
  k_merge<<<ROWSc * 16 / 256, 256, 0, stream>>>(Op, Mp, Lp, AOb, S);
  k_gemm_out<<<dim3(Ec / 128, Mc / 128), 256, 0, stream>>>(AOb, WoT, bout, out);
}

// Round 5
// 219.435 us; speedup vs baseline: 1.6099x; 1.2403x over previous
//
#include <hip/hip_runtime.h>
#include <hip/hip_bf16.h>
#include <cstdint>
#include <cstddef>

// YatAttention on MI355X (gfx950).
// B=2, L=2048, E=768, H=12, D=64. GEMMs in bf16 MFMA 16x16x32 (fp32 accum).
// R7 (resubmit; previous round was an infra failure, kernel never ran):
// back to R4's proven k_attn staging (K+V glds16 dbuf -- R5/R6 showed
// removing it un-hides L2 latency). New: (a) exp2-domain softmax (m tracked
// in log2 units, log2e folded into the score muls, exp2f = native v_exp);
// (b) T13 defer-rescale: skip O-rescale when __all(rmax <= mi + 11.54);
// (c) S=1 with in-kernel normalize -> k_merge deleted, no Op/Mp/Lp traffic,
// grid 768 = exactly 3 blocks/CU (LDS cap) = one fully-resident cohort.

typedef __bf16 bf16_t;
typedef __bf16 bf16x8 __attribute__((ext_vector_type(8)));
typedef __bf16 bf16x4 __attribute__((ext_vector_type(4)));
typedef float floatx4 __attribute__((ext_vector_type(4)));

#define DEVI static __device__ __forceinline__

#define Bc 2
#define Lc 2048
#define Ec 768
#define Hc 12
#define Dc 64
#define N3c 2304
#define Mc 4096
#define ROWSc (Bc * Hc * Lc)  // 49152

DEVI void glds16(const bf16_t* g, bf16_t* l) {
  __builtin_amdgcn_global_load_lds(
      (const __attribute__((address_space(1))) void*)g,
      (__attribute__((address_space(3))) void*)l, 16, 0, 0);
}

// ---------------- conversion kernels ----------------

__global__ __launch_bounds__(256) void k_cvt(const float* __restrict__ in,
                                             bf16_t* __restrict__ out, int n) {
  int i = (blockIdx.x * 256 + threadIdx.x) * 4;
  if (i >= n) return;
  float4 v = *(const float4*)(in + i);
  bf16x4 o;
  o[0] = (bf16_t)v.x; o[1] = (bf16_t)v.y; o[2] = (bf16_t)v.z; o[3] = (bf16_t)v.w;
  *(bf16x4*)(out + i) = o;
}

__global__ __launch_bounds__(256) void k_tc(const float* __restrict__ in,
                                            bf16_t* __restrict__ out, int R, int C) {
  __shared__ float tile[32][33];
  int c0 = blockIdx.x * 32, r0 = blockIdx.y * 32;
  int tx = threadIdx.x, ty = threadIdx.y;
  #pragma unroll
  for (int i = 0; i < 32; i += 8)
    tile[ty + i][tx] = in[(size_t)(r0 + ty + i) * C + c0 + tx];
  __syncthreads();
  #pragma unroll
  for (int i = 0; i < 32; i += 8)
    out[(size_t)(c0 + ty + i) * R + r0 + tx] = (bf16_t)tile[tx][ty + i];
}

// ---------------- GEMM core (m97 pattern) ----------------

DEVI void gemm_core(const bf16_t* __restrict__ A, const bf16_t* __restrict__ Bt,
                    bf16_t* lA, bf16_t* lB, int m0, int n0, floatx4 (&acc)[4][4]) {
  const int tid = threadIdx.x, wave = tid >> 6, lane = tid & 63;
  const int wm = (wave >> 1) * 64, wn = (wave & 1) * 64;
  const int lrow = lane >> 2, lseg = lane & 3;
  const int quad = lane >> 4, r16 = lane & 15;
  for (int kk = 0; kk < 768; kk += 32) {
    glds16(A  + (size_t)(m0 + wave * 32      + lrow) * 768 + kk + lseg * 8, lA + (wave * 32) * 32);
    glds16(A  + (size_t)(m0 + wave * 32 + 16 + lrow) * 768 + kk + lseg * 8, lA + (wave * 32 + 16) * 32);
    glds16(Bt + (size_t)(n0 + wave * 32      + lrow) * 768 + kk + lseg * 8, lB + (wave * 32) * 32);
    glds16(Bt + (size_t)(n0 + wave * 32 + 16 + lrow) * 768 + kk + lseg * 8, lB + (wave * 32 + 16) * 32);
    __syncthreads();
    bf16x8 af[4], bv[4];
    #pragma unroll
    for (int mi = 0; mi < 4; mi++)
      af[mi] = *(const bf16x8*)(lA + (wm + mi * 16 + r16) * 32 + quad * 8);
    #pragma unroll
    for (int ni = 0; ni < 4; ni++)
      bv[ni] = *(const bf16x8*)(lB + (wn + ni * 16 + r16) * 32 + quad * 8);
    #pragma unroll
    for (int mi = 0; mi < 4; mi++)
      #pragma unroll
      for (int ni = 0; ni < 4; ni++)
        acc[mi][ni] = __builtin_amdgcn_mfma_f32_16x16x32_bf16(af[mi], bv[ni], acc[mi][ni], 0, 0, 0);
    __syncthreads();
  }
}

__global__ __launch_bounds__(256) void k_gemm_qkv(
    const bf16_t* __restrict__ A, const bf16_t* __restrict__ Bt,
    const float* __restrict__ bias,
    bf16_t* __restrict__ Qo, bf16_t* __restrict__ Ko, bf16_t* __restrict__ Vo) {
  __shared__ bf16_t lA[128 * 32];
  __shared__ bf16_t lB[128 * 32];
  const int m0 = blockIdx.y * 128, n0 = blockIdx.x * 128;
  const int tid = threadIdx.x, wave = tid >> 6, lane = tid & 63;
  const int wm = (wave >> 1) * 64, wn = (wave & 1) * 64;
  const int quad = lane >> 4, r16 = lane & 15;
  floatx4 acc[4][4] = {};
  gemm_core(A, Bt, lA, lB, m0, n0, acc);

  const int sec = n0 / 768;
  bf16_t* dst = (sec == 0) ? Qo : ((sec == 1) ? Ko : Vo);
  #pragma unroll
  for (int ni = 0; ni < 4; ni++) {
    const int n = n0 + wn + ni * 16 + r16;
    const int nn = n - sec * 768;
    const int h = nn >> 6, d = nn & 63;
    const float bvs = bias[n];
    #pragma unroll
    for (int mi = 0; mi < 4; mi++) {
      #pragma unroll
      for (int reg = 0; reg < 4; reg++) {
        const int m = m0 + wm + mi * 16 + quad * 4 + reg;
        const int b = m >> 11, l = m & 2047;
        const float v = acc[mi][ni][reg] + bvs;
        dst[(((size_t)(b * Hc + h)) * Lc + l) * Dc + d] = (bf16_t)v;
      }
    }
  }
}

__global__ __launch_bounds__(256) void k_gemm_out(
    const bf16_t* __restrict__ A, const bf16_t* __restrict__ Bt,
    const float* __restrict__ bias, float* __restrict__ out) {
  __shared__ bf16_t lA[128 * 32];
  __shared__ bf16_t lB[128 * 32];
  const int m0 = blockIdx.y * 128, n0 = blockIdx.x * 128;
  const int tid = threadIdx.x, wave = tid >> 6, lane = tid & 63;
  const int wm = (wave >> 1) * 64, wn = (wave & 1) * 64;
  const int quad = lane >> 4, r16 = lane & 15;
  floatx4 acc[4][4] = {};
  gemm_core(A, Bt, lA, lB, m0, n0, acc);
  #pragma unroll
  for (int ni = 0; ni < 4; ni++) {
    const int n = n0 + wn + ni * 16 + r16;
    const float bvs = bias[n];
    #pragma unroll
    for (int mi = 0; mi < 4; mi++) {
      #pragma unroll
      for (int reg = 0; reg < 4; reg++) {
        const int m = m0 + wm + mi * 16 + quad * 4 + reg;
        out[(size_t)m * Ec + n] = acc[mi][ni][reg] + bvs;
      }
    }
  }
}

// ---------------- q_sq / k_sq (ksq carries +eps) + mask bias ----------------
__global__ __launch_bounds__(256) void k_sq(const bf16_t* __restrict__ Q,
                                            const bf16_t* __restrict__ K,
                                            const int* __restrict__ mask,
                                            float* __restrict__ qsq, float* __restrict__ ksq,
                                            float* __restrict__ mbias) {
  const int row = blockIdx.x * 256 + threadIdx.x;
  const bf16x8* q = (const bf16x8*)(Q + (size_t)row * 64);
  const bf16x8* k = (const bf16x8*)(K + (size_t)row * 64);
  float sq = 0.f, sk = 0.f;
  #pragma unroll
  for (int c = 0; c < 8; c++) {
    bf16x8 vq = q[c], vk = k[c];
    #pragma unroll
    for (int j = 0; j < 8; j++) {
      float a = (float)vq[j]; sq += a * a;
      float b = (float)vk[j]; sk += b * b;
    }
  }
  qsq[row] = sq;
  ksq[row] = sk + 1e-6f;
  const int bh = row >> 11, l = row & 2047;
  if (bh == 0 || bh == Hc) {  // one (b,*) representative per batch
    const int b = bh / Hc;
    // log2-domain bias: 0 (keep) or -1e30 (exp2 -> 0)
    mbias[b * Lc + l] = (mask[b * Lc + l] == 1) ? 0.f : -1e30f;
  }
}

// ---------------- V transpose ----------------
__global__ __launch_bounds__(256) void k_vt(const bf16_t* __restrict__ V,
                                            bf16_t* __restrict__ VT) {
  __shared__ bf16_t t[64][72];
  const int gid = blockIdx.x;
  const int bh = gid >> 5, j0 = (gid & 31) * 64;
  const int tid = threadIdx.x;
  const bf16_t* Vh = V + ((size_t)bh * Lc) * Dc;
  bf16_t* VTh = VT + ((size_t)bh * Dc) * Lc;
  #pragma unroll
  for (int it = 0; it < 2; ++it) {
    int c = tid + it * 256;
    int j = c >> 3, seg = c & 7;
    *(bf16x8*)&t[j][seg * 8] = *(const bf16x8*)(Vh + (size_t)(j0 + j) * 64 + seg * 8);
  }
  __syncthreads();
  #pragma unroll
  for (int it = 0; it < 2; ++it) {
    int c = tid + it * 256;
    int d = c >> 3, jseg = c & 7;
    bf16x8 o;
    #pragma unroll
    for (int u = 0; u < 8; u++) o[u] = t[jseg * 8 + u][d];
    *(bf16x8*)(VTh + (size_t)d * Lc + j0 + jseg * 8) = o;
  }
}

// ---------------- flash attention: R4 staging + exp2/defer softmax, S=1 ----
// grid = 768. Block: 4 waves, 64 queries (wave = 16). Key tile = 64.
// K+V tiles staged via glds16 dbuf (XOR-swizzled chunks, conflict-free
// ds_read_b128). S^T = K.Q^T scores; O^T = VT.P^T -> softmax state per-lane
// (query = r16). m tracked in log2 domain; defer-rescale (T13, THR=8*log2e);
// final normalize + bf16 AO write in-kernel (no merge pass).
__global__ __launch_bounds__(256) void k_attn(
    const bf16_t* __restrict__ Q, const bf16_t* __restrict__ K,
    const bf16_t* __restrict__ VT, const float* __restrict__ qsq,
    const float* __restrict__ ksq, const float* __restrict__ mbias,
    bf16_t* __restrict__ AO) {
  __shared__ bf16_t lK[2][4096];   // 64 keys x 64 d, swizzled 16B chunks
  __shared__ bf16_t lV[2][4096];   // 64 d x 64 keys, swizzled 16B chunks
  __shared__ bf16_t lP[4][16 * 72];
  const int gid0 = blockIdx.x;
  const int gid = (gid0 & 7) * 96 + (gid0 >> 3);  // XCD swizzle: 3 bh per XCD
  const int bh = gid >> 5, qt = gid & 31;
  const int b = bh / Hc;
  const int h = bh - b * Hc;
  const int tid = threadIdx.x, wave = tid >> 6, lane = tid & 63;
  const int quad = lane >> 4, r16 = lane & 15;
  const int q0 = qt * 64 + wave * 16;
  const bf16_t* Qh = Q + ((size_t)bh * Lc) * Dc;
  const bf16_t* Kh = K + ((size_t)bh * Lc) * Dc;
  const bf16_t* VTh = VT + ((size_t)bh * Dc) * Lc;
  const float* qsqh = qsq + bh * Lc;
  const float* ksqh = ksq + bh * Lc;
  const float* mbb = mbias + b * Lc;
  bf16_t* myP = &lP[wave][0];

  // --- staging geometry: chunk p = i*256 + wave*64 + lane covers row p>>3,
  // slot p&7 which holds global chunk (p&7)^((p>>3)&7).
  const int p0 = wave * 64 + lane;         // inst 0; inst 1 = p0 + 256 (row+32)
  const int srow = p0 >> 3;                // 0..31
  const int sj = (p0 & 7) ^ (srow & 7);    // swizzled global chunk
  const bf16_t* kg0 = Kh + (size_t)srow * 64 + sj * 8;
  const bf16_t* kg1 = kg0 + 32 * 64;
  const bf16_t* vg0 = VTh + (size_t)srow * Lc + sj * 8;
  const bf16_t* vg1 = vg0 + 32 * Lc;
  // LDS dests (wave-uniform): chunk base (i*256 + wave*64)*8 elements
  const int ld0 = wave * 64 * 8, ld1 = (256 + wave * 64) * 8;

  // fragment read offsets (swizzled slots), elements
  const int sl0 = ((quad ^ (r16 & 7)) * 8);
  const int sl1 = sl0 ^ 32;  // chunk quad+4

  // Q B-fragments + per-lane query state
  bf16x8 qf0 = *(const bf16x8*)(Qh + (size_t)(q0 + r16) * 64 + quad * 8);
  bf16x8 qf1 = *(const bf16x8*)(Qh + (size_t)(q0 + r16) * 64 + 32 + quad * 8);
  const float qs = qsqh[q0 + r16];
  float mi = -1e30f, li = 0.f;   // mi in LOG2 domain
  floatx4 of[4] = {};  // O^T: lane holds O^T[d=t4*16+quad*4+reg][q=r16]

  // prologue: stage tile 0 into buf 0
  glds16(kg0, &lK[0][ld0]);
  glds16(kg1, &lK[0][ld1]);
  glds16(vg0, &lV[0][ld0]);
  glds16(vg1, &lV[0][ld1]);
  kg0 += 4096; kg1 += 4096; vg0 += 64; vg1 += 64;
  __syncthreads();

  const int nt = Lc / 64;  // 32
  for (int t = 0; t < nt; t++) {
    const int cur = t & 1;
    if (t + 1 < nt) {
      const int nxt = cur ^ 1;
      glds16(kg0, &lK[nxt][ld0]);
      glds16(kg1, &lK[nxt][ld1]);
      glds16(vg0, &lV[nxt][ld0]);
      glds16(vg1, &lV[nxt][ld1]);
      kg0 += 4096; kg1 += 4096; vg0 += 64; vg1 += 64;
    }
    const int kt = t * 64;
    // ksq/mask-bias for this lane's 16 keys (c*16 + quad*4 + reg)
    float4 ks4[4], mb4[4];
    #pragma unroll
    for (int c = 0; c < 4; c++) {
      ks4[c] = *(const float4*)(ksqh + kt + c * 16 + quad * 4);
      mb4[c] = *(const float4*)(mbb + kt + c * 16 + quad * 4);
    }
    // S^T MFMAs from LDS K tile
    floatx4 dot[4];
    #pragma unroll
    for (int c = 0; c < 4; c++) {
      const int rbase = (c * 16 + r16) * 64;
      bf16x8 kf0 = *(const bf16x8*)(&lK[cur][rbase + sl0]);
      bf16x8 kf1 = *(const bf16x8*)(&lK[cur][rbase + sl1]);
      floatx4 a = {};
      a = __builtin_amdgcn_mfma_f32_16x16x32_bf16(kf0, qf0, a, 0, 0, 0);
      a = __builtin_amdgcn_mfma_f32_16x16x32_bf16(kf1, qf1, a, 0, 0, 0);
      dot[c] = a;
    }
    // transform to log2-domain scores (lane owns 16 scores of query r16);
    // sc2 = (dd*log2e)*dd * rcp(den) + mbv  (mbv: 0 or -1e30)
    float rmax = -1e30f;
    #pragma unroll
    for (int c = 0; c < 4; c++) {
      #pragma unroll
      for (int reg = 0; reg < 4; reg++) {
        const float dd = dot[c][reg];
        const float kss = ((const float*)&ks4[c])[reg];  // has +eps
        const float mbv = ((const float*)&mb4[c])[reg];
        const float den = __builtin_fmaf(dd, -2.f, qs + kss);
        const float sc = __builtin_fmaf((dd * 1.44269504f) * dd,
                                        __builtin_amdgcn_rcpf(den), mbv);
        dot[c][reg] = sc;
        rmax = fmaxf(rmax, sc);
      }
    }
    rmax = fmaxf(rmax, __shfl_xor(rmax, 16));
    rmax = fmaxf(rmax, __shfl_xor(rmax, 32));
    // T13 defer-rescale: only rescale when some query's max grew > 2^11.54
    if (!__all(rmax <= mi + 11.5416f)) {
      const float mnew = fmaxf(mi, rmax);
      const float alpha = exp2f(mi - mnew);
      li *= alpha;
      #pragma unroll
      for (int t4 = 0; t4 < 4; t4++) {
        #pragma unroll
        for (int reg = 0; reg < 4; reg++) of[t4][reg] *= alpha;
      }
      mi = mnew;
    }
    float psum = 0.f;
    #pragma unroll
    for (int c = 0; c < 4; c++) {
      bf16x4 pk;
      #pragma unroll
      for (int reg = 0; reg < 4; reg++) {
        const float p = exp2f(dot[c][reg] - mi);  // masked: exp2(-huge)=0
        psum += p;
        pk[reg] = (bf16_t)p;
      }
      *(bf16x4*)(myP + r16 * 72 + c * 16 + quad * 4) = pk;
    }
    psum += __shfl_xor(psum, 16);
    psum += __shfl_xor(psum, 32);
    li += psum;
    // O^T += VT . P^T : A = VT frag (m=d), B = P frag (n=query)
    bf16x8 pf0 = *(const bf16x8*)(myP + r16 * 72 + quad * 8);
    bf16x8 pf1 = *(const bf16x8*)(myP + r16 * 72 + 32 + quad * 8);
    #pragma unroll
    for (int t4 = 0; t4 < 4; t4++) {
      const int rbase = (t4 * 16 + r16) * 64;
      bf16x8 vf0 = *(const bf16x8*)(&lV[cur][rbase + sl0]);
      bf16x8 vf1 = *(const bf16x8*)(&lV[cur][rbase + sl1]);
      of[t4] = __builtin_amdgcn_mfma_f32_16x16x32_bf16(vf0, pf0, of[t4], 0, 0, 0);
      of[t4] = __builtin_amdgcn_mfma_f32_16x16x32_bf16(vf1, pf1, of[t4], 0, 0, 0);
    }
    __syncthreads();
  }
  // epilogue: normalize and write bf16 AO[(b*Lc+l)*Ec + h*64 + d] directly
  const float inv = (li > 0.f) ? __builtin_amdgcn_rcpf(li) : 0.f;
  bf16_t* aor = AO + ((size_t)(b * Lc + q0 + r16)) * Ec + h * 64;
  #pragma unroll
  for (int t4 = 0; t4 < 4; t4++) {
    bf16x4 o;
    #pragma unroll
    for (int reg = 0; reg < 4; reg++) o[reg] = (bf16_t)(of[t4][reg] * inv);
    *(bf16x4*)(aor + t4 * 16 + quad * 4) = o;
  }
}

// ---------------- launch ----------------

extern "C" void kernel_launch(void* const* d_in, const int* in_sizes, int n_in,
                              void* d_out, int out_size, void* d_ws, size_t ws_size,
                              hipStream_t stream) {
  const float* x    = (const float*)d_in[0];
  const int*   mask = (const int*)d_in[1];
  const float* Wqkv = (const float*)d_in[2];
  const float* bqkv = (const float*)d_in[3];
  const float* Wout = (const float*)d_in[4];
  const float* bout = (const float*)d_in[5];
  float* out = (float*)d_out;

  auto al = [](size_t x) { return (x + 255) & ~(size_t)255; };
  char* ws = (char*)d_ws;
  size_t off = 0;
  auto carve = [&](size_t bytes) -> char* {
    char* p = ws + off;
    off += al(bytes);
    return p;
  };
  bf16_t* WoT = (bf16_t*)carve((size_t)Ec * Ec * 2);
  bf16_t* Qb  = (bf16_t*)carve((size_t)ROWSc * Dc * 2);
  bf16_t* Kb  = (bf16_t*)carve((size_t)ROWSc * Dc * 2);
  bf16_t* VTb = (bf16_t*)carve((size_t)ROWSc * Dc * 2);
  bf16_t* AOb = (bf16_t*)carve((size_t)Mc * Ec * 2);
  float*  qsq = (float*)carve((size_t)ROWSc * 4);
  float*  ksq = (float*)carve((size_t)ROWSc * 4);
  float*  mbias = (float*)carve((size_t)Bc * Lc * 4);
  const size_t uni = off;
  bf16_t* xb  = (bf16_t*)(ws + uni);
  bf16_t* WqT = (bf16_t*)(ws + uni + al((size_t)Mc * Ec * 2));
  bf16_t* Vb  = (bf16_t*)(ws + uni + al((size_t)Mc * Ec * 2) + al((size_t)N3c * Ec * 2));
  (void)in_sizes; (void)n_in; (void)out_size; (void)ws_size;

  k_cvt<<<(Mc * Ec / 4 + 255) / 256, 256, 0, stream>>>(x, xb, Mc * Ec);
  k_tc<<<dim3(N3c / 32, Ec / 32), dim3(32, 8), 0, stream>>>(Wqkv, WqT, Ec, N3c);
  k_tc<<<dim3(Ec / 32, Ec / 32), dim3(32, 8), 0, stream>>>(Wout, WoT, Ec, Ec);
  k_gemm_qkv<<<dim3(N3c / 128, Mc / 128), 256, 0, stream>>>(xb, WqT, bqkv, Qb, Kb, Vb);
  k_sq<<<ROWSc / 256, 256, 0, stream>>>(Qb, Kb, mask, qsq, ksq, mbias);
  k_vt<<<ROWSc / 64, 256, 0, stream>>>(Vb, VTb);
  k_attn<<<dim3(ROWSc / 64), 256, 0, stream>>>(Qb, Kb, VTb, qsq, ksq, mbias, AOb);
  k_gemm_out<<<dim3(Ec / 128, Mc / 128), 256, 0, stream>>>(AOb, WoT, bout, out);
}

// Round 6
// 210.387 us; speedup vs baseline: 1.6792x; 1.0430x over previous
//
#include <hip/hip_runtime.h>
#include <hip/hip_bf16.h>
#include <cstdint>
#include <cstddef>

// YatAttention on MI355X (gfx950).
// B=2, L=2048, E=768, H=12, D=64. GEMMs in bf16 MFMA 16x16x32 (fp32 accum).
// R8: chain surgery on R7's proven k_attn (R7 showed VALU-op trims are flat ->
// kernel is serial-chain latency-bound, not VALU-throughput-bound):
//  (1) rmax shuffles gated behind the defer branch (per-lane max suffices to
//      evaluate the gate; common path has ZERO cross-lane ops before exp);
//  (2) li kept as per-lane partial, reduced once in epilogue (removes the 2
//      psum shuffles from every tile);
//  (3) ks4/mb4 register-prefetched one tile ahead (L2 latency off the chain).
// Also: launch fusion within dependency levels: {cvt,tc,tc}->k_prep,
// {sq,vt}->k_prep2. 8 -> 5 dispatches.

typedef __bf16 bf16_t;
typedef __bf16 bf16x8 __attribute__((ext_vector_type(8)));
typedef __bf16 bf16x4 __attribute__((ext_vector_type(4)));
typedef float floatx4 __attribute__((ext_vector_type(4)));

#define DEVI static __device__ __forceinline__

#define Bc 2
#define Lc 2048
#define Ec 768
#define Hc 12
#define Dc 64
#define N3c 2304
#define Mc 4096
#define ROWSc (Bc * Hc * Lc)  // 49152

DEVI void glds16(const bf16_t* g, bf16_t* l) {
  __builtin_amdgcn_global_load_lds(
      (const __attribute__((address_space(1))) void*)g,
      (__attribute__((address_space(3))) void*)l, 16, 0, 0);
}

// ---------------- fused prep: fp32->bf16 cvt + two weight transposes -------
// blocks [0,3072): cvt of x (4096x768 floats, 4/thread)
// blocks [3072,4800): transpose Wqkv (768 x 2304) -> WqT
// blocks [4800,5376): transpose Wout (768 x 768) -> WoT
__global__ __launch_bounds__(256) void k_prep(
    const float* __restrict__ x, bf16_t* __restrict__ xb,
    const float* __restrict__ Wqkv, bf16_t* __restrict__ WqT,
    const float* __restrict__ Wout, bf16_t* __restrict__ WoT) {
  __shared__ float tile[32][33];
  const int bid = blockIdx.x, tid = threadIdx.x;
  if (bid < 3072) {
    const int i = (bid * 256 + tid) * 4;
    float4 v = *(const float4*)(x + i);
    bf16x4 o;
    o[0] = (bf16_t)v.x; o[1] = (bf16_t)v.y; o[2] = (bf16_t)v.z; o[3] = (bf16_t)v.w;
    *(bf16x4*)(xb + i) = o;
    return;
  }
  const float* in; bf16_t* out; int C, local;
  if (bid < 4800) { local = bid - 3072; in = Wqkv; out = WqT; C = N3c; }
  else            { local = bid - 4800; in = Wout; out = WoT; C = Ec;  }
  const int R = Ec;
  const int nbx = C / 32;
  const int c0 = (local % nbx) * 32, r0 = (local / nbx) * 32;
  const int tx = tid & 31, ty = tid >> 5;
  #pragma unroll
  for (int i = 0; i < 32; i += 8)
    tile[ty + i][tx] = in[(size_t)(r0 + ty + i) * C + c0 + tx];
  __syncthreads();
  #pragma unroll
  for (int i = 0; i < 32; i += 8)
    out[(size_t)(c0 + ty + i) * R + r0 + tx] = (bf16_t)tile[tx][ty + i];
}

// ---------------- GEMM core (m97 pattern) ----------------

DEVI void gemm_core(const bf16_t* __restrict__ A, const bf16_t* __restrict__ Bt,
                    bf16_t* lA, bf16_t* lB, int m0, int n0, floatx4 (&acc)[4][4]) {
  const int tid = threadIdx.x, wave = tid >> 6, lane = tid & 63;
  const int wm = (wave >> 1) * 64, wn = (wave & 1) * 64;
  const int lrow = lane >> 2, lseg = lane & 3;
  const int quad = lane >> 4, r16 = lane & 15;
  for (int kk = 0; kk < 768; kk += 32) {
    glds16(A  + (size_t)(m0 + wave * 32      + lrow) * 768 + kk + lseg * 8, lA + (wave * 32) * 32);
    glds16(A  + (size_t)(m0 + wave * 32 + 16 + lrow) * 768 + kk + lseg * 8, lA + (wave * 32 + 16) * 32);
    glds16(Bt + (size_t)(n0 + wave * 32      + lrow) * 768 + kk + lseg * 8, lB + (wave * 32) * 32);
    glds16(Bt + (size_t)(n0 + wave * 32 + 16 + lrow) * 768 + kk + lseg * 8, lB + (wave * 32 + 16) * 32);
    __syncthreads();
    bf16x8 af[4], bv[4];
    #pragma unroll
    for (int mi = 0; mi < 4; mi++)
      af[mi] = *(const bf16x8*)(lA + (wm + mi * 16 + r16) * 32 + quad * 8);
    #pragma unroll
    for (int ni = 0; ni < 4; ni++)
      bv[ni] = *(const bf16x8*)(lB + (wn + ni * 16 + r16) * 32 + quad * 8);
    #pragma unroll
    for (int mi = 0; mi < 4; mi++)
      #pragma unroll
      for (int ni = 0; ni < 4; ni++)
        acc[mi][ni] = __builtin_amdgcn_mfma_f32_16x16x32_bf16(af[mi], bv[ni], acc[mi][ni], 0, 0, 0);
    __syncthreads();
  }
}

__global__ __launch_bounds__(256) void k_gemm_qkv(
    const bf16_t* __restrict__ A, const bf16_t* __restrict__ Bt,
    const float* __restrict__ bias,
    bf16_t* __restrict__ Qo, bf16_t* __restrict__ Ko, bf16_t* __restrict__ Vo) {
  __shared__ bf16_t lA[128 * 32];
  __shared__ bf16_t lB[128 * 32];
  const int m0 = blockIdx.y * 128, n0 = blockIdx.x * 128;
  const int tid = threadIdx.x, wave = tid >> 6, lane = tid & 63;
  const int wm = (wave >> 1) * 64, wn = (wave & 1) * 64;
  const int quad = lane >> 4, r16 = lane & 15;
  floatx4 acc[4][4] = {};
  gemm_core(A, Bt, lA, lB, m0, n0, acc);

  const int sec = n0 / 768;
  bf16_t* dst = (sec == 0) ? Qo : ((sec == 1) ? Ko : Vo);
  #pragma unroll
  for (int ni = 0; ni < 4; ni++) {
    const int n = n0 + wn + ni * 16 + r16;
    const int nn = n - sec * 768;
    const int h = nn >> 6, d = nn & 63;
    const float bvs = bias[n];
    #pragma unroll
    for (int mi = 0; mi < 4; mi++) {
      #pragma unroll
      for (int reg = 0; reg < 4; reg++) {
        const int m = m0 + wm + mi * 16 + quad * 4 + reg;
        const int b = m >> 11, l = m & 2047;
        const float v = acc[mi][ni][reg] + bvs;
        dst[(((size_t)(b * Hc + h)) * Lc + l) * Dc + d] = (bf16_t)v;
      }
    }
  }
}

__global__ __launch_bounds__(256) void k_gemm_out(
    const bf16_t* __restrict__ A, const bf16_t* __restrict__ Bt,
    const float* __restrict__ bias, float* __restrict__ out) {
  __shared__ bf16_t lA[128 * 32];
  __shared__ bf16_t lB[128 * 32];
  const int m0 = blockIdx.y * 128, n0 = blockIdx.x * 128;
  const int tid = threadIdx.x, wave = tid >> 6, lane = tid & 63;
  const int wm = (wave >> 1) * 64, wn = (wave & 1) * 64;
  const int quad = lane >> 4, r16 = lane & 15;
  floatx4 acc[4][4] = {};
  gemm_core(A, Bt, lA, lB, m0, n0, acc);
  #pragma unroll
  for (int ni = 0; ni < 4; ni++) {
    const int n = n0 + wn + ni * 16 + r16;
    const float bvs = bias[n];
    #pragma unroll
    for (int mi = 0; mi < 4; mi++) {
      #pragma unroll
      for (int reg = 0; reg < 4; reg++) {
        const int m = m0 + wm + mi * 16 + quad * 4 + reg;
        out[(size_t)m * Ec + n] = acc[mi][ni][reg] + bvs;
      }
    }
  }
}

// ------- fused prep2: q_sq/k_sq (+eps, mask bias) + V transpose -------
// blocks [0,192): k_sq body. blocks [192,960): V transpose.
__global__ __launch_bounds__(256) void k_prep2(
    const bf16_t* __restrict__ Q, const bf16_t* __restrict__ K,
    const int* __restrict__ mask,
    float* __restrict__ qsq, float* __restrict__ ksq,
    float* __restrict__ mbias,
    const bf16_t* __restrict__ V, bf16_t* __restrict__ VT) {
  __shared__ bf16_t tb[64][72];
  const int bid = blockIdx.x, tid = threadIdx.x;
  if (bid < 192) {
    const int row = bid * 256 + tid;
    const bf16x8* q = (const bf16x8*)(Q + (size_t)row * 64);
    const bf16x8* k = (const bf16x8*)(K + (size_t)row * 64);
    float sq = 0.f, sk = 0.f;
    #pragma unroll
    for (int c = 0; c < 8; c++) {
      bf16x8 vq = q[c], vk = k[c];
      #pragma unroll
      for (int j = 0; j < 8; j++) {
        float a = (float)vq[j]; sq += a * a;
        float b = (float)vk[j]; sk += b * b;
      }
    }
    qsq[row] = sq;
    ksq[row] = sk + 1e-6f;
    const int bh = row >> 11, l = row & 2047;
    if (bh == 0 || bh == Hc) {
      const int b = bh / Hc;
      mbias[b * Lc + l] = (mask[b * Lc + l] == 1) ? 0.f : -1e30f;
    }
    return;
  }
  const int gid = bid - 192;
  const int bh = gid >> 5, j0 = (gid & 31) * 64;
  const bf16_t* Vh = V + ((size_t)bh * Lc) * Dc;
  bf16_t* VTh = VT + ((size_t)bh * Dc) * Lc;
  #pragma unroll
  for (int it = 0; it < 2; ++it) {
    int c = tid + it * 256;
    int j = c >> 3, seg = c & 7;
    *(bf16x8*)&tb[j][seg * 8] = *(const bf16x8*)(Vh + (size_t)(j0 + j) * 64 + seg * 8);
  }
  __syncthreads();
  #pragma unroll
  for (int it = 0; it < 2; ++it) {
    int c = tid + it * 256;
    int d = c >> 3, jseg = c & 7;
    bf16x8 o;
    #pragma unroll
    for (int u = 0; u < 8; u++) o[u] = tb[jseg * 8 + u][d];
    *(bf16x8*)(VTh + (size_t)d * Lc + j0 + jseg * 8) = o;
  }
}

// ---------------- flash attention: R7 staging + chain-trimmed softmax ------
// grid = 768. Block: 4 waves, 64 queries (wave = 16). Key tile = 64.
// K+V glds16 dbuf (XOR-swizzled, conflict-free ds_read_b128). S^T = K.Q^T;
// O^T = VT.P^T; softmax state per-lane (query = r16, lane owns 16 keys).
// Chain trims: rmax shuffles gated behind defer branch; li per-lane partial
// (epilogue reduce); ks/mb prefetched one tile ahead.
__global__ __launch_bounds__(256) void k_attn(
    const bf16_t* __restrict__ Q, const bf16_t* __restrict__ K,
    const bf16_t* __restrict__ VT, const float* __restrict__ qsq,
    const float* __restrict__ ksq, const float* __restrict__ mbias,
    bf16_t* __restrict__ AO) {
  __shared__ bf16_t lK[2][4096];   // 64 keys x 64 d, swizzled 16B chunks
  __shared__ bf16_t lV[2][4096];   // 64 d x 64 keys, swizzled 16B chunks
  __shared__ bf16_t lP[4][16 * 72];
  const int gid0 = blockIdx.x;
  const int gid = (gid0 & 7) * 96 + (gid0 >> 3);  // XCD swizzle: 3 bh per XCD
  const int bh = gid >> 5, qt = gid & 31;
  const int b = bh / Hc;
  const int h = bh - b * Hc;
  const int tid = threadIdx.x, wave = tid >> 6, lane = tid & 63;
  const int quad = lane >> 4, r16 = lane & 15;
  const int q0 = qt * 64 + wave * 16;
  const bf16_t* Qh = Q + ((size_t)bh * Lc) * Dc;
  const bf16_t* Kh = K + ((size_t)bh * Lc) * Dc;
  const bf16_t* VTh = VT + ((size_t)bh * Dc) * Lc;
  const float* qsqh = qsq + bh * Lc;
  const float* ksqh = ksq + bh * Lc;
  const float* mbb = mbias + b * Lc;
  bf16_t* myP = &lP[wave][0];

  // staging geometry (as R4/R7)
  const int p0 = wave * 64 + lane;
  const int srow = p0 >> 3;
  const int sj = (p0 & 7) ^ (srow & 7);
  const bf16_t* kg0 = Kh + (size_t)srow * 64 + sj * 8;
  const bf16_t* kg1 = kg0 + 32 * 64;
  const bf16_t* vg0 = VTh + (size_t)srow * Lc + sj * 8;
  const bf16_t* vg1 = vg0 + 32 * Lc;
  const int ld0 = wave * 64 * 8, ld1 = (256 + wave * 64) * 8;

  const int sl0 = ((quad ^ (r16 & 7)) * 8);
  const int sl1 = sl0 ^ 32;

  bf16x8 qf0 = *(const bf16x8*)(Qh + (size_t)(q0 + r16) * 64 + quad * 8);
  bf16x8 qf1 = *(const bf16x8*)(Qh + (size_t)(q0 + r16) * 64 + 32 + quad * 8);
  const float qs = qsqh[q0 + r16];
  float mi = -1e30f;        // LOG2 domain, shared across the query's 4 lanes
  float li = 0.f;           // PER-LANE partial (own 16 keys); reduced at end
  floatx4 of[4] = {};

  // prologue: stage tile 0; ks/mb for tile 0
  glds16(kg0, &lK[0][ld0]);
  glds16(kg1, &lK[0][ld1]);
  glds16(vg0, &lV[0][ld0]);
  glds16(vg1, &lV[0][ld1]);
  kg0 += 4096; kg1 += 4096; vg0 += 64; vg1 += 64;
  float4 ks4[4], mb4[4];
  #pragma unroll
  for (int c = 0; c < 4; c++) {
    ks4[c] = *(const float4*)(ksqh + c * 16 + quad * 4);
    mb4[c] = *(const float4*)(mbb + c * 16 + quad * 4);
  }
  __syncthreads();

  const int nt = Lc / 64;  // 32
  for (int t = 0; t < nt; t++) {
    const int cur = t & 1;
    const bool more = (t + 1 < nt);
    if (more) {
      const int nxt = cur ^ 1;
      glds16(kg0, &lK[nxt][ld0]);
      glds16(kg1, &lK[nxt][ld1]);
      glds16(vg0, &lV[nxt][ld0]);
      glds16(vg1, &lV[nxt][ld1]);
      kg0 += 4096; kg1 += 4096; vg0 += 64; vg1 += 64;
    }
    // prefetch next tile's ksq/mbias into regs (consumed next iteration)
    float4 ks4n[4], mb4n[4];
    if (more) {
      const int ktn = (t + 1) * 64;
      #pragma unroll
      for (int c = 0; c < 4; c++) {
        ks4n[c] = *(const float4*)(ksqh + ktn + c * 16 + quad * 4);
        mb4n[c] = *(const float4*)(mbb + ktn + c * 16 + quad * 4);
      }
    }
    // S^T MFMAs from LDS K tile
    floatx4 dot[4];
    #pragma unroll
    for (int c = 0; c < 4; c++) {
      const int rbase = (c * 16 + r16) * 64;
      bf16x8 kf0 = *(const bf16x8*)(&lK[cur][rbase + sl0]);
      bf16x8 kf1 = *(const bf16x8*)(&lK[cur][rbase + sl1]);
      floatx4 a = {};
      a = __builtin_amdgcn_mfma_f32_16x16x32_bf16(kf0, qf0, a, 0, 0, 0);
      a = __builtin_amdgcn_mfma_f32_16x16x32_bf16(kf1, qf1, a, 0, 0, 0);
      dot[c] = a;
    }
    // transform to log2-domain scores; per-lane max only
    float rmax = -1e30f;
    #pragma unroll
    for (int c = 0; c < 4; c++) {
      #pragma unroll
      for (int reg = 0; reg < 4; reg++) {
        const float dd = dot[c][reg];
        const float kss = ((const float*)&ks4[c])[reg];  // has +eps
        const float mbv = ((const float*)&mb4[c])[reg];
        const float den = __builtin_fmaf(dd, -2.f, qs + kss);
        const float sc = __builtin_fmaf((dd * 1.44269504f) * dd,
                                        __builtin_amdgcn_rcpf(den), mbv);
        dot[c][reg] = sc;
        rmax = fmaxf(rmax, sc);
      }
    }
    // Gated rescale: shuffles + rescale ONLY when some lane's local max
    // exceeds mi + THR (P bounded by 2^11.54 otherwise; first tile triggers).
    if (!__all(rmax <= mi + 11.5416f)) {
      float rg = fmaxf(rmax, __shfl_xor(rmax, 16));
      rg = fmaxf(rg, __shfl_xor(rg, 32));
      const float mnew = fmaxf(mi, rg);
      const float alpha = exp2f(mi - mnew);
      li *= alpha;
      #pragma unroll
      for (int t4 = 0; t4 < 4; t4++) {
        #pragma unroll
        for (int reg = 0; reg < 4; reg++) of[t4][reg] *= alpha;
      }
      mi = mnew;
    }
    float psum = 0.f;
    #pragma unroll
    for (int c = 0; c < 4; c++) {
      bf16x4 pk;
      #pragma unroll
      for (int reg = 0; reg < 4; reg++) {
        const float p = exp2f(dot[c][reg] - mi);  // masked: exp2(-huge)=0
        psum += p;
        pk[reg] = (bf16_t)p;
      }
      *(bf16x4*)(myP + r16 * 72 + c * 16 + quad * 4) = pk;
    }
    li += psum;  // per-lane partial; no cross-lane reduce in the loop
    // O^T += VT . P^T
    bf16x8 pf0 = *(const bf16x8*)(myP + r16 * 72 + quad * 8);
    bf16x8 pf1 = *(const bf16x8*)(myP + r16 * 72 + 32 + quad * 8);
    #pragma unroll
    for (int t4 = 0; t4 < 4; t4++) {
      const int rbase = (t4 * 16 + r16) * 64;
      bf16x8 vf0 = *(const bf16x8*)(&lV[cur][rbase + sl0]);
      bf16x8 vf1 = *(const bf16x8*)(&lV[cur][rbase + sl1]);
      of[t4] = __builtin_amdgcn_mfma_f32_16x16x32_bf16(vf0, pf0, of[t4], 0, 0, 0);
      of[t4] = __builtin_amdgcn_mfma_f32_16x16x32_bf16(vf1, pf1, of[t4], 0, 0, 0);
    }
    if (more) {
      #pragma unroll
      for (int c = 0; c < 4; c++) { ks4[c] = ks4n[c]; mb4[c] = mb4n[c]; }
    }
    __syncthreads();
  }
  // epilogue: reduce li across the query's 4 lanes, normalize, write bf16 AO
  li += __shfl_xor(li, 16);
  li += __shfl_xor(li, 32);
  const float inv = (li > 0.f) ? __builtin_amdgcn_rcpf(li) : 0.f;
  bf16_t* aor = AO + ((size_t)(b * Lc + q0 + r16)) * Ec + h * 64;
  #pragma unroll
  for (int t4 = 0; t4 < 4; t4++) {
    bf16x4 o;
    #pragma unroll
    for (int reg = 0; reg < 4; reg++) o[reg] = (bf16_t)(of[t4][reg] * inv);
    *(bf16x4*)(aor + t4 * 16 + quad * 4) = o;
  }
}

// ---------------- launch ----------------

extern "C" void kernel_launch(void* const* d_in, const int* in_sizes, int n_in,
                              void* d_out, int out_size, void* d_ws, size_t ws_size,
                              hipStream_t stream) {
  const float* x    = (const float*)d_in[0];
  const int*   mask = (const int*)d_in[1];
  const float* Wqkv = (const float*)d_in[2];
  const float* bqkv = (const float*)d_in[3];
  const float* Wout = (const float*)d_in[4];
  const float* bout = (const float*)d_in[5];
  float* out = (float*)d_out;

  auto al = [](size_t x) { return (x + 255) & ~(size_t)255; };
  char* ws = (char*)d_ws;
  size_t off = 0;
  auto carve = [&](size_t bytes) -> char* {
    char* p = ws + off;
    off += al(bytes);
    return p;
  };
  bf16_t* WoT = (bf16_t*)carve((size_t)Ec * Ec * 2);
  bf16_t* Qb  = (bf16_t*)carve((size_t)ROWSc * Dc * 2);
  bf16_t* Kb  = (bf16_t*)carve((size_t)ROWSc * Dc * 2);
  bf16_t* VTb = (bf16_t*)carve((size_t)ROWSc * Dc * 2);
  bf16_t* AOb = (bf16_t*)carve((size_t)Mc * Ec * 2);
  float*  qsq = (float*)carve((size_t)ROWSc * 4);
  float*  ksq = (float*)carve((size_t)ROWSc * 4);
  float*  mbias = (float*)carve((size_t)Bc * Lc * 4);
  const size_t uni = off;
  bf16_t* xb  = (bf16_t*)(ws + uni);
  bf16_t* WqT = (bf16_t*)(ws + uni + al((size_t)Mc * Ec * 2));
  bf16_t* Vb  = (bf16_t*)(ws + uni + al((size_t)Mc * Ec * 2) + al((size_t)N3c * Ec * 2));
  (void)in_sizes; (void)n_in; (void)out_size; (void)ws_size;

  k_prep<<<5376, 256, 0, stream>>>(x, xb, Wqkv, WqT, Wout, WoT);
  k_gemm_qkv<<<dim3(N3c / 128, Mc / 128), 256, 0, stream>>>(xb, WqT, bqkv, Qb, Kb, Vb);
  k_prep2<<<960, 256, 0, stream>>>(Qb, Kb, mask, qsq, ksq, mbias, Vb, VTb);
  k_attn<<<dim3(ROWSc / 64), 256, 0, stream>>>(Qb, Kb, VTb, qsq, ksq, mbias, AOb);
  k_gemm_out<<<dim3(Ec / 128, Mc / 128), 256, 0, stream>>>(AOb, WoT, bout, out);
}